// Round 1
// baseline (100.635 us; speedup 1.0000x reference)
//
#include <hip/hip_runtime.h>

// SpatialLocalSum: out[b,hw,s] = log( sum_c exp(x[b,hw,c]) * acc[hw,c,s] ) - log(sum_c acc[hw,c,s])
// (reference's mx/mw stabilizers cancel algebraically; exp(x) safe for x~N(0,1))
//
// R7: b-dimension split across two blocks (grid 2048, 64 b-rows each) to break
// the grid-limited 4-blocks/CU occupancy cap (grid 1024 == 4/CU exactly; phase-
// lockstep blocks left HBM idle during epilogue -> 4.5 TB/s effective of 6.3).
// __launch_bounds__(256,8) caps VGPR at 64 -> 8 blocks/CU, 32 waves/CU.
// acc is read by both b-half blocks of an hw; halves are 1024 apart in
// blockIdx (same XCD, 1024%8==0) and acc (16MB) is L3-resident, so the second
// read should stay off HBM. MFMA/LDS layout identical to the verified kernel.

typedef __attribute__((ext_vector_type(8))) short s8v;   // 8 bf16 (A/B fragment)
typedef __attribute__((ext_vector_type(4))) float f4v;   // 4 fp32

__device__ __forceinline__ unsigned short f2bf(float f) {
    unsigned int u = __float_as_uint(f);
    u += 0x7FFFu + ((u >> 16) & 1u);   // round-to-nearest-even
    return (unsigned short)(u >> 16);
}

__global__ __launch_bounds__(256, 8) void sls_kernel(
    const float* __restrict__ x,     // [128,1024,64]
    const float* __restrict__ acc,   // [1024,64,64]  (c,s) per hw
    float* __restrict__ out)         // [128,1024,64]
{
    const int hw   = blockIdx.x & 1023;
    const int bb   = (blockIdx.x >> 10) << 6;   // b-half base: 0 or 64
    const int t    = threadIdx.x;
    const int quad = (t >> 4) & 3;
    const int nn   = t & 15;
    const int wave = t >> 6;

    // e (bf16) row-major, stride 72 elems (144B): b128-aligned frag reads, ~2-way max.
    __shared__ unsigned short e_lds[64 * 72];   // 9.2 KB -> LDS allows 8 blocks/CU

    const int r0 = t >> 4;           // 0..15
    const int c0 = (t & 15) * 4;     // 0..60

    // ---- issue all global loads up front: acc (16 strided scalars), x (4x16B) ----
    const float* accb = acc + (size_t)hw * 4096 + wave * 16 + nn;
    float bv[2][8];
    #pragma unroll
    for (int ks = 0; ks < 2; ++ks)
        #pragma unroll
        for (int j = 0; j < 8; ++j)
            bv[ks][j] = accb[(ks * 32 + quad * 8 + j) * 64];

    const float* xbase = x + (size_t)(bb + r0) * 65536 + (size_t)hw * 64 + c0;
    f4v xv[4];
    #pragma unroll
    for (int it = 0; it < 4; ++it)
        xv[it] = *(const f4v*)(xbase + (size_t)(16 * it) * 65536);

    // ---- e = bf16(exp(x)) -> LDS ----
    #pragma unroll
    for (int it = 0; it < 4; ++it) {
        f4v v = xv[it];
        ushort4 pk;
        pk.x = f2bf(__expf(v.x));
        pk.y = f2bf(__expf(v.y));
        pk.z = f2bf(__expf(v.z));
        pk.w = f2bf(__expf(v.w));
        *(ushort4*)&e_lds[(r0 + 16 * it) * 72 + c0] = pk;
    }

    // ---- column sums + B fragments ----
    float csum = 0.f;
    #pragma unroll
    for (int ks = 0; ks < 2; ++ks)
        #pragma unroll
        for (int j = 0; j < 8; ++j) csum += bv[ks][j];
    csum += __shfl_xor(csum, 16);
    csum += __shfl_xor(csum, 32);
    const float lsum_n = __logf(csum);

    s8v bf0, bf1;
    #pragma unroll
    for (int j = 0; j < 8; ++j) {
        bf0[j] = (short)f2bf(bv[0][j]);
        bf1[j] = (short)f2bf(bv[1][j]);
    }

    __syncthreads();

    // ---- MFMA + epilogue ----
    float* outp = out + (size_t)bb * 65536 + (size_t)hw * 64 + wave * 16 + nn;
    #pragma unroll
    for (int mi = 0; mi < 4; ++mi) {
        const unsigned short* rowp = &e_lds[(mi * 16 + nn) * 72];
        s8v a0 = *(const s8v*)(rowp + quad * 8);
        s8v a1 = *(const s8v*)(rowp + 32 + quad * 8);
        f4v d = {0.f, 0.f, 0.f, 0.f};
        d = __builtin_amdgcn_mfma_f32_16x16x32_bf16(a0, bf0, d, 0, 0, 0);
        d = __builtin_amdgcn_mfma_f32_16x16x32_bf16(a1, bf1, d, 0, 0, 0);
        #pragma unroll
        for (int r = 0; r < 4; ++r) {
            const int b_row = mi * 16 + quad * 4 + r;   // C/D: row=(lane>>4)*4+r, col=lane&15
            __builtin_nontemporal_store(__logf(d[r]) - lsum_n, outp + (size_t)b_row * 65536);
        }
    }
}

extern "C" void kernel_launch(void* const* d_in, const int* in_sizes, int n_in,
                              void* d_out, int out_size, void* d_ws, size_t ws_size,
                              hipStream_t stream) {
    const float* x   = (const float*)d_in[0];
    const float* acc = (const float*)d_in[1];
    float* out = (float*)d_out;
    (void)in_sizes; (void)n_in; (void)d_ws; (void)ws_size; (void)out_size;
    sls_kernel<<<dim3(2048), dim3(256), 0, stream>>>(x, acc, out);
}

// Round 2
// 97.027 us; speedup vs baseline: 1.0372x; 1.0372x over previous
//
#include <hip/hip_runtime.h>

// SpatialLocalSum: out[b,hw,s] = log( sum_c exp(x[b,hw,c]) * acc[hw,c,s] ) - log(sum_c acc[hw,c,s])
// (reference's mx/mw stabilizers cancel algebraically; exp(x) safe for x~N(0,1))
//
// R8: one block per hw (grid 1024, 4 blocks/CU) but 512 threads = 8 waves:
// wave w owns (s-tile = w&3, b-half = w>>2). 32 waves/CU (max) WITHOUT the
// acc-traffic duplication that sank R7 (the two waves sharing an s-tile read
// identical 4KB of acc -> L1 hit on the same CU; HBM traffic identical to R6).
// One barrier instead of two; per-wave MFMA/epilogue tail halves, so the
// phase-lockstep HBM-idle windows shrink while 2x waves cover them.
// __launch_bounds__(512,8) caps VGPR at 64 (live estimate ~50, no spill).

typedef __attribute__((ext_vector_type(8))) short s8v;   // 8 bf16 (A/B fragment)
typedef __attribute__((ext_vector_type(4))) float f4v;   // 4 fp32

__device__ __forceinline__ unsigned short f2bf(float f) {
    unsigned int u = __float_as_uint(f);
    u += 0x7FFFu + ((u >> 16) & 1u);   // round-to-nearest-even
    return (unsigned short)(u >> 16);
}

__global__ __launch_bounds__(512, 8) void sls_kernel(
    const float* __restrict__ x,     // [128,1024,64]
    const float* __restrict__ acc,   // [1024,64,64]  (c,s) per hw
    float* __restrict__ out)         // [128,1024,64]
{
    const int hw   = blockIdx.x;
    const int t    = threadIdx.x;
    const int lane = t & 63;
    const int quad = lane >> 4;
    const int nn   = lane & 15;
    const int wave = t >> 6;         // 0..7
    const int ni   = wave & 3;       // s-tile
    const int bh   = wave >> 2;      // b-half

    // e (bf16) row-major, stride 72 elems (144B): b128-aligned frag reads, ~2-way max.
    __shared__ unsigned short e_lds[2][64 * 72];   // 18.4 KB; 4 blocks/CU -> 74 KB

    const int r0 = t >> 4;           // 0..31 (staging row base, spans waves)
    const int c0 = (t & 15) * 4;     // 0..60

    // ---- issue all global loads up front: x (4x16B rows, stride 32), acc ----
    const float* xbase = x + (size_t)hw * 64 + c0;
    f4v xv[4];
    #pragma unroll
    for (int it = 0; it < 4; ++it)
        xv[it] = *(const f4v*)(xbase + (size_t)(r0 + 32 * it) * 65536);

    const float* accb = acc + (size_t)hw * 4096 + ni * 16 + nn;
    float bv[2][8];
    #pragma unroll
    for (int ks = 0; ks < 2; ++ks)
        #pragma unroll
        for (int j = 0; j < 8; ++j)
            bv[ks][j] = accb[(ks * 32 + quad * 8 + j) * 64];

    // ---- e = bf16(exp(x)) -> LDS (acc loads still in flight) ----
    #pragma unroll
    for (int it = 0; it < 4; ++it) {
        f4v v = xv[it];
        const int row = r0 + 32 * it;          // 0..127, unique per (t,it)
        ushort4 pk;
        pk.x = f2bf(__expf(v.x));
        pk.y = f2bf(__expf(v.y));
        pk.z = f2bf(__expf(v.z));
        pk.w = f2bf(__expf(v.w));
        *(ushort4*)&e_lds[row >> 6][(row & 63) * 72 + c0] = pk;
    }

    // ---- column sums + B fragments ----
    float csum = 0.f;
    #pragma unroll
    for (int ks = 0; ks < 2; ++ks)
        #pragma unroll
        for (int j = 0; j < 8; ++j) csum += bv[ks][j];
    csum += __shfl_xor(csum, 16);
    csum += __shfl_xor(csum, 32);
    const float lsum_n = __logf(csum);

    s8v bf0, bf1;
    #pragma unroll
    for (int j = 0; j < 8; ++j) {
        bf0[j] = (short)f2bf(bv[0][j]);
        bf1[j] = (short)f2bf(bv[1][j]);
    }

    __syncthreads();

    // ---- MFMA + epilogue: each wave does its (s-tile, b-half) quadrant ----
    float* outp = out + (size_t)hw * 64 + ni * 16 + nn;
    #pragma unroll
    for (int mi = 0; mi < 4; ++mi) {
        const unsigned short* rowp = &e_lds[bh][(mi * 16 + nn) * 72];
        s8v a0 = *(const s8v*)(rowp + quad * 8);
        s8v a1 = *(const s8v*)(rowp + 32 + quad * 8);
        f4v d = {0.f, 0.f, 0.f, 0.f};
        d = __builtin_amdgcn_mfma_f32_16x16x32_bf16(a0, bf0, d, 0, 0, 0);
        d = __builtin_amdgcn_mfma_f32_16x16x32_bf16(a1, bf1, d, 0, 0, 0);
        #pragma unroll
        for (int r = 0; r < 4; ++r) {
            const int b_row = (bh << 6) + mi * 16 + quad * 4 + r;   // C/D: row=(lane>>4)*4+r, col=lane&15
            __builtin_nontemporal_store(__logf(d[r]) - lsum_n, outp + (size_t)b_row * 65536);
        }
    }
}

extern "C" void kernel_launch(void* const* d_in, const int* in_sizes, int n_in,
                              void* d_out, int out_size, void* d_ws, size_t ws_size,
                              hipStream_t stream) {
    const float* x   = (const float*)d_in[0];
    const float* acc = (const float*)d_in[1];
    float* out = (float*)d_out;
    (void)in_sizes; (void)n_in; (void)d_ws; (void)ws_size; (void)out_size;
    sls_kernel<<<dim3(1024), dim3(512), 0, stream>>>(x, acc, out);
}